// Round 6
// baseline (308.463 us; speedup 1.0000x reference)
//
#include <hip/hip_runtime.h>

#define N_NODES 50000
#define N_EDGES 800000
#define D 256

#define NPART ((N_NODES + 255) / 256)      // 196 scan blocks
#define XBLKS ((N_NODES * D / 4 + 255) / 256)  // 12500 convert blocks (exact)

typedef __attribute__((ext_vector_type(8))) short short8;
typedef __attribute__((ext_vector_type(4))) float f32x4;

typedef const __attribute__((address_space(1))) unsigned int* as1_u32p;
typedef __attribute__((address_space(3))) unsigned int* as3_u32p;

__device__ __forceinline__ unsigned short f2bf(float f) {
    unsigned int u = __float_as_uint(f);
    u = (u + 0x7fffu + ((u >> 16) & 1u)) >> 16;   // RTNE
    return (unsigned short)u;
}

// --- fused convert: x fp32->bf16 (blocks [0,XBLKS)), W transpose+convert --
__global__ __launch_bounds__(256) void convert_xw(const float4* __restrict__ x,
                                                  ushort4* __restrict__ xh,
                                                  const float* __restrict__ W,
                                                  unsigned short* __restrict__ Wt) {
    int b = blockIdx.x;
    if (b < XBLKS) {
        int i = b * 256 + threadIdx.x;            // exactly N_NODES*D/4
        float4 v = x[i];
        xh[i] = make_ushort4(f2bf(v.x), f2bf(v.y), f2bf(v.z), f2bf(v.w));
    } else {
        int idx = (b - XBLKS) * 256 + threadIdx.x; // 65536 = D*D
        int k = idx >> 8, n = idx & 255;
        Wt[n * 256 + k] = f2bf(W[idx]);
    }
}

// --- CSR step 1: histogram, 4 edges per thread ---------------------------
__global__ __launch_bounds__(256) void hist_kernel(const int4* __restrict__ erow4,
                                                   int* __restrict__ cnt) {
    int i = blockIdx.x * 256 + threadIdx.x;       // over N_EDGES/4 = 200000
    if (i >= N_EDGES / 4) return;
    int4 r = erow4[i];
    atomicAdd(&cnt[r.x], 1);
    atomicAdd(&cnt[r.y], 1);
    atomicAdd(&cnt[r.z], 1);
    atomicAdd(&cnt[r.w], 1);
}

// --- CSR step 2: single-pass decoupled-lookback exclusive scan -----------
// 196 blocks (all trivially co-resident on 256 CUs -> spin is safe).
// bstate[b]: bits 31:30 = flag (1=aggregate ready, 2=prefix ready),
//            bits 29:0 = value. Zeroed by the memset alongside cnt.
__global__ __launch_bounds__(256) void scan_lookback_kernel(const int* __restrict__ cnt,
                                                            unsigned int* __restrict__ bstate,
                                                            int* __restrict__ row_start,
                                                            int* __restrict__ cursor) {
    __shared__ int s[256];
    __shared__ int s_off;
    int b = blockIdx.x, t = threadIdx.x;
    int idx = b * 256 + t;
    int v = (idx < N_NODES) ? cnt[idx] : 0;
    s[t] = v;
    __syncthreads();
    for (int off = 1; off < 256; off <<= 1) {
        int u = (t >= off) ? s[t - off] : 0;
        __syncthreads();
        s[t] += u;
        __syncthreads();
    }
    int incl  = s[t];
    int total = s[255];
    if (t == 0) {
        if (b == 0) {
            __hip_atomic_store(&bstate[0], (2u << 30) | (unsigned)total,
                               __ATOMIC_RELEASE, __HIP_MEMORY_SCOPE_AGENT);
            s_off = 0;
        } else {
            __hip_atomic_store(&bstate[b], (1u << 30) | (unsigned)total,
                               __ATOMIC_RELEASE, __HIP_MEMORY_SCOPE_AGENT);
            int run = 0;
            for (int p = b - 1; p >= 0;) {
                unsigned st;
                do {
                    st = __hip_atomic_load(&bstate[p], __ATOMIC_ACQUIRE,
                                           __HIP_MEMORY_SCOPE_AGENT);
                } while ((st >> 30) == 0u);
                run += (int)(st & 0x3fffffffu);
                if ((st >> 30) == 2u) break;
                --p;
            }
            __hip_atomic_store(&bstate[b], (2u << 30) | (unsigned)(run + total),
                               __ATOMIC_RELEASE, __HIP_MEMORY_SCOPE_AGENT);
            s_off = run;
        }
    }
    __syncthreads();
    int excl = s_off + incl - v;
    if (idx < N_NODES) {
        row_start[idx] = excl;
        cursor[idx]    = excl;
    }
    if (b == 0 && t == 0) row_start[N_NODES] = N_EDGES;
}

// --- CSR step 3: scatter payloads ----------------------------------------
__global__ __launch_bounds__(256) void scatter_kernel(const int* __restrict__ erow,
                                                      const int* __restrict__ ecol,
                                                      const float* __restrict__ evals,
                                                      int* __restrict__ cursor,
                                                      int2* __restrict__ spay) {
    int e = blockIdx.x * 256 + threadIdx.x;
    if (e >= N_EDGES) return;
    int r = erow[e];
    int pos = atomicAdd(&cursor[r], 1);
    spay[pos] = make_int2(ecol[e], __float_as_int(evals[e]));
}

// --- Aggregation: wave per row, unroll x8 for memory-level parallelism ---
__global__ __launch_bounds__(256) void aggregate_kernel(const unsigned short* __restrict__ xh,
                                                        const int* __restrict__ row_start,
                                                        const int2* __restrict__ spay,
                                                        unsigned short* __restrict__ aggh) {
    int gid  = blockIdx.x * 256 + threadIdx.x;
    int row  = gid >> 6;
    int lane = threadIdx.x & 63;
    if (row >= N_NODES) return;
    int s = row_start[row];
    int e = row_start[row + 1];
    float a0 = 0.f, a1 = 0.f, a2 = 0.f, a3 = 0.f;
    int i = s;
    for (; i + 8 <= e; i += 8) {
        int2 p[8];
        uint2 q[8];
#pragma unroll
        for (int j = 0; j < 8; ++j) p[j] = spay[i + j];
#pragma unroll
        for (int j = 0; j < 8; ++j)
            q[j] = ((const uint2*)(xh + (size_t)p[j].x * D))[lane];
#pragma unroll
        for (int j = 0; j < 8; ++j) {
            float v = __int_as_float(p[j].y);
            a0 += v * __uint_as_float(q[j].x << 16);
            a1 += v * __uint_as_float(q[j].x & 0xffff0000u);
            a2 += v * __uint_as_float(q[j].y << 16);
            a3 += v * __uint_as_float(q[j].y & 0xffff0000u);
        }
    }
    for (; i + 4 <= e; i += 4) {
        int2 p[4];
        uint2 q[4];
#pragma unroll
        for (int j = 0; j < 4; ++j) p[j] = spay[i + j];
#pragma unroll
        for (int j = 0; j < 4; ++j)
            q[j] = ((const uint2*)(xh + (size_t)p[j].x * D))[lane];
#pragma unroll
        for (int j = 0; j < 4; ++j) {
            float v = __int_as_float(p[j].y);
            a0 += v * __uint_as_float(q[j].x << 16);
            a1 += v * __uint_as_float(q[j].x & 0xffff0000u);
            a2 += v * __uint_as_float(q[j].y << 16);
            a3 += v * __uint_as_float(q[j].y & 0xffff0000u);
        }
    }
    for (; i < e; ++i) {
        int2  p = spay[i];
        float v = __int_as_float(p.y);
        uint2 q = ((const uint2*)(xh + (size_t)p.x * D))[lane];
        a0 += v * __uint_as_float(q.x << 16);
        a1 += v * __uint_as_float(q.x & 0xffff0000u);
        a2 += v * __uint_as_float(q.y << 16);
        a3 += v * __uint_as_float(q.y & 0xffff0000u);
    }
    ushort4 o = make_ushort4(f2bf(a0), f2bf(a1), f2bf(a2), f2bf(a3));
    ((ushort4*)(aggh + (size_t)row * D))[lane] = o;
}

// --- GEMM: bf16 MFMA, 128x128 tile, BK=32, fused bias+relu ---------------
__global__ __launch_bounds__(256) void gemm_mfma(const unsigned short* __restrict__ A,
                                                 const unsigned short* __restrict__ Wt,
                                                 const float* __restrict__ bias,
                                                 float* __restrict__ out) {
    __shared__ unsigned short As[128 * 32];
    __shared__ unsigned short Bs[128 * 32];

    int t    = threadIdx.x;
    int w    = t >> 6;
    int lane = t & 63;
    int wm   = w & 1;
    int wn   = w >> 1;
    int mblk = blockIdx.x >> 1;
    int nblk = blockIdx.x & 1;
    int m0   = mblk * 128;
    int n0   = nblk * 128;

    f32x4 acc[4][4];
#pragma unroll
    for (int i = 0; i < 4; ++i)
#pragma unroll
        for (int j = 0; j < 4; ++j) acc[i][j] = (f32x4){0.f, 0.f, 0.f, 0.f};

    int lq = lane >> 2;
    int lr = lane & 3;

    for (int k0 = 0; k0 < D; k0 += 32) {
#pragma unroll
        for (int i = 0; i < 2; ++i) {
            int r0 = i * 64 + w * 16;
            int gm = m0 + r0 + lq;
            if (gm > N_NODES - 1) gm = N_NODES - 1;
            const unsigned short* gp = A + (size_t)gm * D + k0 + lr * 8;
            __builtin_amdgcn_global_load_lds((as1_u32p)gp, (as3_u32p)(As + r0 * 32), 16, 0, 0);
        }
#pragma unroll
        for (int i = 0; i < 2; ++i) {
            int r0 = i * 64 + w * 16;
            int gn = n0 + r0 + lq;
            const unsigned short* gp = Wt + (size_t)gn * D + k0 + lr * 8;
            __builtin_amdgcn_global_load_lds((as1_u32p)gp, (as3_u32p)(Bs + r0 * 32), 16, 0, 0);
        }
        __syncthreads();

        short8 af[4], bf[4];
        int kq = (lane >> 4) * 8;
        int lm = lane & 15;
#pragma unroll
        for (int mt = 0; mt < 4; ++mt)
            af[mt] = *(const short8*)(As + (wm * 64 + mt * 16 + lm) * 32 + kq);
#pragma unroll
        for (int nt = 0; nt < 4; ++nt)
            bf[nt] = *(const short8*)(Bs + (wn * 64 + nt * 16 + lm) * 32 + kq);
#pragma unroll
        for (int mt = 0; mt < 4; ++mt)
#pragma unroll
            for (int nt = 0; nt < 4; ++nt)
                acc[mt][nt] = __builtin_amdgcn_mfma_f32_16x16x32_bf16(af[mt], bf[nt], acc[mt][nt], 0, 0, 0);
        __syncthreads();
    }

    int cl = lane & 15;
    int cr = (lane >> 4) * 4;
#pragma unroll
    for (int nt = 0; nt < 4; ++nt) {
        int n = n0 + wn * 64 + nt * 16 + cl;
        float b = bias[n];
#pragma unroll
        for (int mt = 0; mt < 4; ++mt) {
            int mbase = m0 + wm * 64 + mt * 16 + cr;
#pragma unroll
            for (int r = 0; r < 4; ++r) {
                int m = mbase + r;
                if (m < N_NODES) {
                    float v = acc[mt][nt][r] + b;
                    out[(size_t)m * D + n] = v > 0.f ? v : 0.f;
                }
            }
        }
    }
}

extern "C" void kernel_launch(void* const* d_in, const int* in_sizes, int n_in,
                              void* d_out, int out_size, void* d_ws, size_t ws_size,
                              hipStream_t stream) {
    const float* x     = (const float*)d_in[0];
    const int*   erow  = (const int*)d_in[1];
    const int*   ecol  = (const int*)d_in[2];
    const float* evals = (const float*)d_in[3];
    const float* W     = (const float*)d_in[4];
    const float* bias  = (const float*)d_in[5];
    float*       out   = (float*)d_out;

    char* ws = (char*)d_ws;
    unsigned short* xh   = (unsigned short*)ws;  ws += (size_t)N_NODES * D * 2;   // 25.6 MB
    unsigned short* aggh = (unsigned short*)ws;  ws += (size_t)N_NODES * D * 2;   // 25.6 MB
    unsigned short* Wt   = (unsigned short*)ws;  ws += (size_t)D * D * 2;         // 128 KB
    int* cnt             = (int*)ws;             ws += (size_t)N_NODES * sizeof(int);
    unsigned int* bstate = (unsigned int*)ws;    ws += 256 * sizeof(unsigned int); // NPART=196, padded
    int* row_start       = (int*)ws;             ws += (size_t)(N_NODES + 1) * sizeof(int);
    int* cursor          = (int*)ws;             ws += (size_t)N_NODES * sizeof(int);
    ws = (char*)(((uintptr_t)ws + 15) & ~(uintptr_t)15);
    int2* spay           = (int2*)ws;                                             // 6.4 MB

    // zero cnt + bstate in one contiguous memset
    hipMemsetAsync(cnt, 0, (size_t)N_NODES * sizeof(int) + 256 * sizeof(unsigned int), stream);

    convert_xw<<<XBLKS + D * D / 256, 256, 0, stream>>>((const float4*)x, (ushort4*)xh, W, Wt);

    hist_kernel<<<(N_EDGES / 4 + 255) / 256, 256, 0, stream>>>((const int4*)erow, cnt);
    scan_lookback_kernel<<<NPART, 256, 0, stream>>>(cnt, bstate, row_start, cursor);
    scatter_kernel<<<(N_EDGES + 255) / 256, 256, 0, stream>>>(erow, ecol, evals, cursor, spay);

    int ablocks = (N_NODES * 64 + 255) / 256;   // 12500
    aggregate_kernel<<<ablocks, 256, 0, stream>>>(xh, row_start, spay, aggh);

    int gblocks = ((N_NODES + 127) / 128) * 2;  // 782
    gemm_mfma<<<gblocks, 256, 0, stream>>>(aggh, Wt, bias, out);
}

// Round 7
// 279.058 us; speedup vs baseline: 1.1054x; 1.1054x over previous
//
#include <hip/hip_runtime.h>

#define N_NODES 50000
#define N_EDGES 800000
#define D 256

#define NPART ((N_NODES + 255) / 256)          // 196 scan blocks
#define HBLKS ((N_EDGES / 4 + 255) / 256)      // 782 hist blocks
#define XBLKS ((N_NODES * D / 4 + 255) / 256)  // 12500 convert-x blocks (exact)
#define WBLKS (D * D / 256)                    // 256 convert-W blocks

typedef __attribute__((ext_vector_type(8))) short short8;
typedef __attribute__((ext_vector_type(4))) float f32x4;

typedef const __attribute__((address_space(1))) unsigned int* as1_u32p;
typedef __attribute__((address_space(3))) unsigned int* as3_u32p;

__device__ __forceinline__ unsigned short f2bf(float f) {
    unsigned int u = __float_as_uint(f);
    u = (u + 0x7fffu + ((u >> 16) & 1u)) >> 16;   // RTNE
    return (unsigned short)u;
}

// --- fused: histogram (blocks [0,HBLKS)) + convert x + convert/transpose W
__global__ __launch_bounds__(256) void convhist_kernel(const int4* __restrict__ erow4,
                                                       int* __restrict__ cnt,
                                                       const float4* __restrict__ x,
                                                       ushort4* __restrict__ xh,
                                                       const float* __restrict__ W,
                                                       unsigned short* __restrict__ Wt) {
    int b = blockIdx.x;
    if (b < HBLKS) {
        int i = b * 256 + threadIdx.x;
        if (i < N_EDGES / 4) {
            int4 r = erow4[i];
            atomicAdd(&cnt[r.x], 1);
            atomicAdd(&cnt[r.y], 1);
            atomicAdd(&cnt[r.z], 1);
            atomicAdd(&cnt[r.w], 1);
        }
    } else if (b < HBLKS + XBLKS) {
        int i = (b - HBLKS) * 256 + threadIdx.x;   // exactly N_NODES*D/4
        float4 v = x[i];
        xh[i] = make_ushort4(f2bf(v.x), f2bf(v.y), f2bf(v.z), f2bf(v.w));
    } else {
        int idx = (b - HBLKS - XBLKS) * 256 + threadIdx.x;  // D*D
        int k = idx >> 8, n = idx & 255;
        Wt[n * 256 + k] = f2bf(W[idx]);
    }
}

// --- single-pass decoupled-lookback scan, WAVE-PARALLEL lookback ---------
// bstate[b]: bits 31:30 flag (1=aggregate ready, 2=prefix ready), 29:0 value.
// 196 blocks, all co-resident on 256 CUs -> spin-wait safe (G16: device scope).
__global__ __launch_bounds__(256) void scan_lookback_kernel(const int* __restrict__ cnt,
                                                            unsigned int* __restrict__ bstate,
                                                            int* __restrict__ row_start,
                                                            int* __restrict__ cursor) {
    __shared__ int s[256];
    __shared__ int s_off;
    int b = blockIdx.x, t = threadIdx.x;
    int idx = b * 256 + t;
    int v = (idx < N_NODES) ? cnt[idx] : 0;
    s[t] = v;
    __syncthreads();
    for (int off = 1; off < 256; off <<= 1) {
        int u = (t >= off) ? s[t - off] : 0;
        __syncthreads();
        s[t] += u;
        __syncthreads();
    }
    int incl  = s[t];
    int total = s[255];

    if (b == 0) {
        if (t == 0) {
            __hip_atomic_store(&bstate[0], (2u << 30) | (unsigned)total,
                               __ATOMIC_RELEASE, __HIP_MEMORY_SCOPE_AGENT);
            s_off = 0;
        }
    } else {
        if (t == 0)
            __hip_atomic_store(&bstate[b], (1u << 30) | (unsigned)total,
                               __ATOMIC_RELEASE, __HIP_MEMORY_SCOPE_AGENT);
        if (t < 64) {
            int run = 0;                 // meaningful on lane 0 only
            int p = b - 1;
            while (true) {
                int i2 = p - t;
                unsigned st = 0;
                if (i2 >= 0) {
                    do {
                        st = __hip_atomic_load(&bstate[i2], __ATOMIC_ACQUIRE,
                                               __HIP_MEMORY_SCOPE_AGENT);
                    } while ((st >> 30) == 0u);
                }
                unsigned long long mask =
                    __ballot((i2 >= 0) && ((st >> 30) == 2u));
                if (mask) {
                    int firstLane = (int)(__ffsll((long long)mask) - 1); // nearest prefix-ready
                    int contrib = (t <= firstLane) ? (int)(st & 0x3fffffffu) : 0;
                    for (int o = 32; o > 0; o >>= 1) contrib += __shfl_down(contrib, o);
                    if (t == 0) run += contrib;
                    break;
                } else {
                    int contrib = (i2 >= 0) ? (int)(st & 0x3fffffffu) : 0;
                    for (int o = 32; o > 0; o >>= 1) contrib += __shfl_down(contrib, o);
                    if (t == 0) run += contrib;
                    p -= 64;             // block 0 is always flag==2, so p>=0 here
                }
            }
            if (t == 0) {
                __hip_atomic_store(&bstate[b], (2u << 30) | (unsigned)(run + total),
                                   __ATOMIC_RELEASE, __HIP_MEMORY_SCOPE_AGENT);
                s_off = run;
            }
        }
    }
    __syncthreads();
    int excl = s_off + incl - v;
    if (idx < N_NODES) {
        row_start[idx] = excl;
        cursor[idx]    = excl;
    }
    if (b == 0 && t == 0) row_start[N_NODES] = N_EDGES;
}

// --- scatter payloads, 4 edges per thread for MLP ------------------------
__global__ __launch_bounds__(256) void scatter_kernel(const int4* __restrict__ erow4,
                                                      const int4* __restrict__ ecol4,
                                                      const float4* __restrict__ evals4,
                                                      int* __restrict__ cursor,
                                                      int2* __restrict__ spay) {
    int i = blockIdx.x * 256 + threadIdx.x;
    if (i >= N_EDGES / 4) return;
    int4   r = erow4[i];
    int4   c = ecol4[i];
    float4 v = evals4[i];
    int p0 = atomicAdd(&cursor[r.x], 1);
    int p1 = atomicAdd(&cursor[r.y], 1);
    int p2 = atomicAdd(&cursor[r.z], 1);
    int p3 = atomicAdd(&cursor[r.w], 1);
    spay[p0] = make_int2(c.x, __float_as_int(v.x));
    spay[p1] = make_int2(c.y, __float_as_int(v.y));
    spay[p2] = make_int2(c.z, __float_as_int(v.z));
    spay[p3] = make_int2(c.w, __float_as_int(v.w));
}

// --- Aggregation: wave per row, unroll x8/x4 for MLP ---------------------
__global__ __launch_bounds__(256) void aggregate_kernel(const unsigned short* __restrict__ xh,
                                                        const int* __restrict__ row_start,
                                                        const int2* __restrict__ spay,
                                                        unsigned short* __restrict__ aggh) {
    int gid  = blockIdx.x * 256 + threadIdx.x;
    int row  = gid >> 6;
    int lane = threadIdx.x & 63;
    if (row >= N_NODES) return;
    int s = row_start[row];
    int e = row_start[row + 1];
    float a0 = 0.f, a1 = 0.f, a2 = 0.f, a3 = 0.f;
    int i = s;
    for (; i + 8 <= e; i += 8) {
        int2 p[8];
        uint2 q[8];
#pragma unroll
        for (int j = 0; j < 8; ++j) p[j] = spay[i + j];
#pragma unroll
        for (int j = 0; j < 8; ++j)
            q[j] = ((const uint2*)(xh + (size_t)p[j].x * D))[lane];
#pragma unroll
        for (int j = 0; j < 8; ++j) {
            float v = __int_as_float(p[j].y);
            a0 += v * __uint_as_float(q[j].x << 16);
            a1 += v * __uint_as_float(q[j].x & 0xffff0000u);
            a2 += v * __uint_as_float(q[j].y << 16);
            a3 += v * __uint_as_float(q[j].y & 0xffff0000u);
        }
    }
    for (; i + 4 <= e; i += 4) {
        int2 p[4];
        uint2 q[4];
#pragma unroll
        for (int j = 0; j < 4; ++j) p[j] = spay[i + j];
#pragma unroll
        for (int j = 0; j < 4; ++j)
            q[j] = ((const uint2*)(xh + (size_t)p[j].x * D))[lane];
#pragma unroll
        for (int j = 0; j < 4; ++j) {
            float v = __int_as_float(p[j].y);
            a0 += v * __uint_as_float(q[j].x << 16);
            a1 += v * __uint_as_float(q[j].x & 0xffff0000u);
            a2 += v * __uint_as_float(q[j].y << 16);
            a3 += v * __uint_as_float(q[j].y & 0xffff0000u);
        }
    }
    for (; i < e; ++i) {
        int2  p = spay[i];
        float v = __int_as_float(p.y);
        uint2 q = ((const uint2*)(xh + (size_t)p.x * D))[lane];
        a0 += v * __uint_as_float(q.x << 16);
        a1 += v * __uint_as_float(q.x & 0xffff0000u);
        a2 += v * __uint_as_float(q.y << 16);
        a3 += v * __uint_as_float(q.y & 0xffff0000u);
    }
    ushort4 o = make_ushort4(f2bf(a0), f2bf(a1), f2bf(a2), f2bf(a3));
    ((ushort4*)(aggh + (size_t)row * D))[lane] = o;
}

// --- GEMM: bf16 MFMA, 128x128 tile, BK=32, fused bias+relu ---------------
__global__ __launch_bounds__(256) void gemm_mfma(const unsigned short* __restrict__ A,
                                                 const unsigned short* __restrict__ Wt,
                                                 const float* __restrict__ bias,
                                                 float* __restrict__ out) {
    __shared__ unsigned short As[128 * 32];
    __shared__ unsigned short Bs[128 * 32];

    int t    = threadIdx.x;
    int w    = t >> 6;
    int lane = t & 63;
    int wm   = w & 1;
    int wn   = w >> 1;
    int mblk = blockIdx.x >> 1;
    int nblk = blockIdx.x & 1;
    int m0   = mblk * 128;
    int n0   = nblk * 128;

    f32x4 acc[4][4];
#pragma unroll
    for (int i = 0; i < 4; ++i)
#pragma unroll
        for (int j = 0; j < 4; ++j) acc[i][j] = (f32x4){0.f, 0.f, 0.f, 0.f};

    int lq = lane >> 2;
    int lr = lane & 3;

    for (int k0 = 0; k0 < D; k0 += 32) {
#pragma unroll
        for (int i = 0; i < 2; ++i) {
            int r0 = i * 64 + w * 16;
            int gm = m0 + r0 + lq;
            if (gm > N_NODES - 1) gm = N_NODES - 1;
            const unsigned short* gp = A + (size_t)gm * D + k0 + lr * 8;
            __builtin_amdgcn_global_load_lds((as1_u32p)gp, (as3_u32p)(As + r0 * 32), 16, 0, 0);
        }
#pragma unroll
        for (int i = 0; i < 2; ++i) {
            int r0 = i * 64 + w * 16;
            int gn = n0 + r0 + lq;
            const unsigned short* gp = Wt + (size_t)gn * D + k0 + lr * 8;
            __builtin_amdgcn_global_load_lds((as1_u32p)gp, (as3_u32p)(Bs + r0 * 32), 16, 0, 0);
        }
        __syncthreads();

        short8 af[4], bf[4];
        int kq = (lane >> 4) * 8;
        int lm = lane & 15;
#pragma unroll
        for (int mt = 0; mt < 4; ++mt)
            af[mt] = *(const short8*)(As + (wm * 64 + mt * 16 + lm) * 32 + kq);
#pragma unroll
        for (int nt = 0; nt < 4; ++nt)
            bf[nt] = *(const short8*)(Bs + (wn * 64 + nt * 16 + lm) * 32 + kq);
#pragma unroll
        for (int mt = 0; mt < 4; ++mt)
#pragma unroll
            for (int nt = 0; nt < 4; ++nt)
                acc[mt][nt] = __builtin_amdgcn_mfma_f32_16x16x32_bf16(af[mt], bf[nt], acc[mt][nt], 0, 0, 0);
        __syncthreads();
    }

    int cl = lane & 15;
    int cr = (lane >> 4) * 4;
#pragma unroll
    for (int nt = 0; nt < 4; ++nt) {
        int n = n0 + wn * 64 + nt * 16 + cl;
        float b = bias[n];
#pragma unroll
        for (int mt = 0; mt < 4; ++mt) {
            int mbase = m0 + wm * 64 + mt * 16 + cr;
#pragma unroll
            for (int r = 0; r < 4; ++r) {
                int m = mbase + r;
                if (m < N_NODES) {
                    float v = acc[mt][nt][r] + b;
                    out[(size_t)m * D + n] = v > 0.f ? v : 0.f;
                }
            }
        }
    }
}

extern "C" void kernel_launch(void* const* d_in, const int* in_sizes, int n_in,
                              void* d_out, int out_size, void* d_ws, size_t ws_size,
                              hipStream_t stream) {
    const float* x     = (const float*)d_in[0];
    const int*   erow  = (const int*)d_in[1];
    const int*   ecol  = (const int*)d_in[2];
    const float* evals = (const float*)d_in[3];
    const float* W     = (const float*)d_in[4];
    const float* bias  = (const float*)d_in[5];
    float*       out   = (float*)d_out;

    char* ws = (char*)d_ws;
    unsigned short* xh   = (unsigned short*)ws;  ws += (size_t)N_NODES * D * 2;   // 25.6 MB
    unsigned short* aggh = (unsigned short*)ws;  ws += (size_t)N_NODES * D * 2;   // 25.6 MB
    unsigned short* Wt   = (unsigned short*)ws;  ws += (size_t)D * D * 2;         // 128 KB
    int* cnt             = (int*)ws;             ws += (size_t)N_NODES * sizeof(int);
    unsigned int* bstate = (unsigned int*)ws;    ws += 256 * sizeof(unsigned int);
    int* row_start       = (int*)ws;             ws += (size_t)(N_NODES + 1) * sizeof(int);
    int* cursor          = (int*)ws;             ws += (size_t)N_NODES * sizeof(int);
    ws = (char*)(((uintptr_t)ws + 15) & ~(uintptr_t)15);
    int2* spay           = (int2*)ws;                                             // 6.4 MB

    // zero cnt + bstate in one contiguous memset
    hipMemsetAsync(cnt, 0, (size_t)N_NODES * sizeof(int) + 256 * sizeof(unsigned int), stream);

    convhist_kernel<<<HBLKS + XBLKS + WBLKS, 256, 0, stream>>>(
        (const int4*)erow, cnt, (const float4*)x, (ushort4*)xh, W, Wt);

    scan_lookback_kernel<<<NPART, 256, 0, stream>>>(cnt, bstate, row_start, cursor);

    scatter_kernel<<<(N_EDGES / 4 + 255) / 256, 256, 0, stream>>>(
        (const int4*)erow, (const int4*)ecol, (const float4*)evals, cursor, spay);

    int ablocks = (N_NODES * 64 + 255) / 256;   // 12500
    aggregate_kernel<<<ablocks, 256, 0, stream>>>(xh, row_start, spay, aggh);

    int gblocks = ((N_NODES + 127) / 128) * 2;  // 782
    gemm_mfma<<<gblocks, 256, 0, stream>>>(aggh, Wt, bias, out);
}